// Round 5
// baseline (145160.352 us; speedup 1.0000x reference)
//
#include <hip/hip_runtime.h>
#include <math.h>

#define E 512
#define S_MAX 32
#define BATCH 32
#define HEADS 8
#define DH 64
#define HID 2048
#define VOCAB 30000
#define NWG 256
#define NTHR 256

typedef unsigned short u16;
typedef __attribute__((ext_vector_type(8))) short short8;
typedef __attribute__((ext_vector_type(4))) float f32x4;

// ---------- bf16 split helpers (RNE) ----------
__device__ __forceinline__ u16 f2bf(float x) {
    union { float f; unsigned u; } v; v.f = x;
    unsigned r = v.u + 0x7fffu + ((v.u >> 16) & 1u);
    return (u16)(r >> 16);
}
__device__ __forceinline__ float bf2f(u16 h) {
    union { unsigned u; float f; } v; v.u = ((unsigned)h) << 16;
    return v.f;
}
__device__ __forceinline__ void split3(float x, u16& h, u16& m, u16& l) {
    h = f2bf(x); float hf = bf2f(h);
    float r1 = x - hf;
    m = f2bf(r1); float mf = bf2f(m);
    l = f2bf(r1 - mf);
}

// ---------- grid barrier (agent scope; all NWG blocks co-resident) ----------
__device__ __noinline__ void gridbar(unsigned* cnt, unsigned* gen) {
    __syncthreads();
    if (threadIdx.x == 0) {
        unsigned g = __hip_atomic_load(gen, __ATOMIC_RELAXED, __HIP_MEMORY_SCOPE_AGENT);
        unsigned v = __hip_atomic_fetch_add(cnt, 1u, __ATOMIC_ACQ_REL, __HIP_MEMORY_SCOPE_AGENT);
        if (v == NWG - 1u) {
            __hip_atomic_store(cnt, 0u, __ATOMIC_RELAXED, __HIP_MEMORY_SCOPE_AGENT);
            __hip_atomic_fetch_add(gen, 1u, __ATOMIC_RELEASE, __HIP_MEMORY_SCOPE_AGENT);
        } else {
            while (__hip_atomic_load(gen, __ATOMIC_ACQUIRE, __HIP_MEMORY_SCOPE_AGENT) == g)
                __builtin_amdgcn_s_sleep(4);
        }
    }
    __syncthreads();
}

// ---------- stage: positional encoding ----------
__device__ __noinline__ void stage_pe(float* __restrict__ PE) {
    for (int i = blockIdx.x * NTHR + threadIdx.x; i < S_MAX * E; i += NWG * NTHR) {
        int s = i >> 9, e = i & (E - 1);
        float expo = (float)(e & ~1) / (float)E;
        float den = powf(10000.0f, expo);
        float ang = (float)s / den;
        PE[i] = (e & 1) ? cosf(ang) : sinf(ang);
    }
}

// ---------- stage: weight split+transpose [K][N]f32 -> [N][K] bf16 x3 ----------
__device__ __noinline__ void wsplit_one(const float* __restrict__ W, u16* __restrict__ Ph,
                                        u16* __restrict__ Pm, u16* __restrict__ Pl,
                                        int K, int N, int Z) {
    long KN = (long)K * N, total = KN * Z;
    for (long i = (long)blockIdx.x * NTHR + threadIdx.x; i < total; i += (long)NWG * NTHR) {
        long z = i / KN; long r = i - z * KN;
        int n = (int)(r / K); int k = (int)(r - (long)n * K);
        float v = W[z * KN + (long)k * N + n];
        u16 h, m, l; split3(v, h, m, l);
        Ph[i] = h; Pm[i] = m; Pl[i] = l;      // i == z*KN + n*K + k
    }
}

// ---------- stage: f32 -> bf16x3 planes ----------
__device__ __noinline__ void split_act(const float* __restrict__ in, long n, u16* __restrict__ Ph,
                                       u16* __restrict__ Pm, u16* __restrict__ Pl) {
    for (long i = (long)blockIdx.x * NTHR + threadIdx.x; i < n; i += (long)NWG * NTHR) {
        u16 h, m, l; split3(in[i], h, m, l);
        Ph[i] = h; Pm[i] = m; Pl[i] = l;
    }
}

// ---------- stage: x = Ybuf + pe (compact), emit splits ----------
__device__ __noinline__ void stage_buildx(float* __restrict__ X, const float* __restrict__ Ybuf,
                                          const float* __restrict__ PE, int Seff,
                                          u16* __restrict__ Xh, u16* __restrict__ Xm,
                                          u16* __restrict__ Xl) {
    long total = (long)BATCH * Seff * E;
    for (long idx = (long)blockIdx.x * NTHR + threadIdx.x; idx < total; idx += (long)NWG * NTHR) {
        int e = (int)(idx & (E - 1));
        long m = idx >> 9;
        int b = (int)(m / Seff);
        int s = (int)(m - (long)b * Seff);
        float v = Ybuf[((long)b * S_MAX + s) * E + e] + PE[s * E + e];
        X[idx] = v;
        u16 h, mm, l; split3(v, h, mm, l);
        Xh[idx] = h; Xm[idx] = mm; Xl[idx] = l;
    }
}

// ---------- stage: MFMA bf16x3-split GEMM (direct-fragment, no LDS) ----------
#define MF(A_, B_, mi, ni) \
    acc[mi][ni] = __builtin_amdgcn_mfma_f32_16x16x32_bf16(A_, B_, acc[mi][ni], 0, 0, 0)

template <int RELU, int WF32, int WSPLIT, int KC>
__device__ __noinline__ void stage_gemm(const u16* __restrict__ Ah, const u16* __restrict__ Am,
                                        const u16* __restrict__ Al,
                                        const u16* __restrict__ Wh, const u16* __restrict__ Wm,
                                        const u16* __restrict__ Wl,
                                        const float* __restrict__ bias,
                                        float* __restrict__ C,
                                        u16* __restrict__ Ch, u16* __restrict__ Cm,
                                        u16* __restrict__ Cl,
                                        int M, int N, int Z, long wz, long cz, long bz) {
    int tid = threadIdx.x, lane = tid & 63, wid = tid >> 6;
    int wr = wid >> 1, wc = wid & 1;
    int mt = (M + 63) >> 6, nt = N >> 6;
    int ntasks = mt * nt * Z;
    for (int task = blockIdx.x; task < ntasks; task += NWG) {
        int z = task / (mt * nt);
        int rr = task - z * mt * nt;
        int tm = rr / nt, tn = rr - tm * nt;
        int m0 = tm * 64, n0 = tn * 64;
        long wzo = (long)z * wz;
        int ra0 = m0 + wr * 32 + (lane & 15); if (ra0 >= M) ra0 = M - 1;
        int ra1 = m0 + wr * 32 + 16 + (lane & 15); if (ra1 >= M) ra1 = M - 1;
        int kcol = (lane >> 4) * 8;
        long ao0 = (long)ra0 * KC + kcol;
        long ao1 = (long)ra1 * KC + kcol;
        long bo0 = (long)(n0 + wc * 32 + (lane & 15)) * KC + kcol + wzo;
        long bo1 = bo0 + 16L * KC;
        f32x4 acc[2][2];
        acc[0][0] = acc[0][1] = acc[1][0] = acc[1][1] = (f32x4){0.f, 0.f, 0.f, 0.f};
#pragma unroll 4
        for (int k0 = 0; k0 < KC; k0 += 32) {
            short8 a0h = *(const short8*)(Ah + ao0 + k0);
            short8 a1h = *(const short8*)(Ah + ao1 + k0);
            short8 a0m = *(const short8*)(Am + ao0 + k0);
            short8 a1m = *(const short8*)(Am + ao1 + k0);
            short8 a0l = *(const short8*)(Al + ao0 + k0);
            short8 a1l = *(const short8*)(Al + ao1 + k0);
            short8 b0h = *(const short8*)(Wh + bo0 + k0);
            short8 b1h = *(const short8*)(Wh + bo1 + k0);
            short8 b0m = *(const short8*)(Wm + bo0 + k0);
            short8 b1m = *(const short8*)(Wm + bo1 + k0);
            short8 b0l = *(const short8*)(Wl + bo0 + k0);
            short8 b1l = *(const short8*)(Wl + bo1 + k0);
            // products: (h,h)(h,m)(m,h)(m,m)(h,l)(l,h)
            MF(a0h, b0h, 0, 0); MF(a0h, b1h, 0, 1); MF(a1h, b0h, 1, 0); MF(a1h, b1h, 1, 1);
            MF(a0h, b0m, 0, 0); MF(a0h, b1m, 0, 1); MF(a1h, b0m, 1, 0); MF(a1h, b1m, 1, 1);
            MF(a0m, b0h, 0, 0); MF(a0m, b1h, 0, 1); MF(a1m, b0h, 1, 0); MF(a1m, b1h, 1, 1);
            MF(a0m, b0m, 0, 0); MF(a0m, b1m, 0, 1); MF(a1m, b0m, 1, 0); MF(a1m, b1m, 1, 1);
            MF(a0h, b0l, 0, 0); MF(a0h, b1l, 0, 1); MF(a1h, b0l, 1, 0); MF(a1h, b1l, 1, 1);
            MF(a0l, b0h, 0, 0); MF(a0l, b1h, 0, 1); MF(a1l, b0h, 1, 0); MF(a1l, b1h, 1, 1);
        }
        const float* bb = bias + (long)z * bz;
        float* Cz = C; u16 *Chz = Ch, *Cmz = Cm, *Clz = Cl;
        if (WF32) Cz = C + (long)z * cz;
        if (WSPLIT) { Chz = Ch + (long)z * cz; Cmz = Cm + (long)z * cz; Clz = Cl + (long)z * cz; }
#pragma unroll
        for (int mi = 0; mi < 2; mi++) {
#pragma unroll
            for (int ni = 0; ni < 2; ni++) {
                int col = n0 + wc * 32 + ni * 16 + (lane & 15);
                float bv = bb[col];
#pragma unroll
                for (int j = 0; j < 4; j++) {
                    int row = m0 + wr * 32 + mi * 16 + (lane >> 4) * 4 + j;
                    if (row < M) {
                        float v = acc[mi][ni][j] + bv;
                        if (RELU) v = fmaxf(v, 0.f);
                        long idx = (long)row * N + col;
                        if (WF32) Cz[idx] = v;
                        if (WSPLIT) {
                            u16 hh, mm, ll; split3(v, hh, mm, ll);
                            Chz[idx] = hh; Cmz[idx] = mm; Clz[idx] = ll;
                        }
                    }
                }
            }
        }
    }
}

// ---------- stage: attention (one wave per (b,h,s) task) ----------
__device__ __noinline__ void stage_attn(const float* __restrict__ Q, const float* __restrict__ Kp,
                                        const float* __restrict__ Vp,
                                        u16* __restrict__ Oh, u16* __restrict__ Om,
                                        u16* __restrict__ Ol,
                                        int Seff, int kvStride) {
    int lane = threadIdx.x & 63;
    int gw = blockIdx.x * 4 + (threadIdx.x >> 6);
    int ntask = Seff * HEADS * BATCH;
    for (int task = gw; task < ntask; task += NWG * 4) {
        int b = task / (Seff * HEADS);
        int r = task - b * Seff * HEADS;
        int h = r / Seff;
        int s = r - h * Seff;
        const float4* q4 = (const float4*)(Q + ((long)(b * Seff + s)) * E + h * DH);
        float sc = -INFINITY;
        if (lane < Seff) {
            const float4* k4 = (const float4*)(Kp + (long)b * kvStride + (long)lane * E + h * DH);
            float acc = 0.f;
#pragma unroll
            for (int d = 0; d < DH / 4; d++) {
                float4 qv = q4[d], kv = k4[d];
                acc += qv.x * kv.x; acc += qv.y * kv.y; acc += qv.z * kv.z; acc += qv.w * kv.w;
            }
            sc = acc * 0.125f;
        }
        float m = sc;
#pragma unroll
        for (int off = 32; off; off >>= 1) m = fmaxf(m, __shfl_xor(m, off));
        float p = (lane < Seff) ? expf(sc - m) : 0.f;
        float sum = p;
#pragma unroll
        for (int off = 32; off; off >>= 1) sum += __shfl_xor(sum, off);
        p = p / sum;
        float accv = 0.f;
        const float* vbase = Vp + (long)b * kvStride + h * DH + lane;
        for (int k = 0; k < Seff; k++) accv = fmaf(__shfl(p, k), vbase[(long)k * E], accv);
        long o = ((long)(b * Seff + s)) * E + h * DH + lane;
        u16 hh, mm, ll; split3(accv, hh, mm, ll);
        Oh[o] = hh; Om[o] = mm; Ol[o] = ll;
    }
}

// ---------- stage: x = LN(x + delta), emit splits (one wave per row) ----------
__device__ __noinline__ void stage_ln(float* __restrict__ X, const float* __restrict__ D,
                                      const float* __restrict__ g, const float* __restrict__ bb,
                                      u16* __restrict__ Xh, u16* __restrict__ Xm,
                                      u16* __restrict__ Xl, int rows) {
    int lane = threadIdx.x & 63;
    for (int row = blockIdx.x * 4 + (threadIdx.x >> 6); row < rows; row += NWG * 4) {
        float* xr = X + (long)row * E;
        const float* dr = D + (long)row * E;
        float v[8]; float s = 0.f;
#pragma unroll
        for (int i = 0; i < 8; i++) { int e = lane + i * 64; v[i] = xr[e] + dr[e]; s += v[i]; }
#pragma unroll
        for (int off = 32; off; off >>= 1) s += __shfl_xor(s, off);
        float mean = s * (1.0f / E);
        float sq = 0.f;
#pragma unroll
        for (int i = 0; i < 8; i++) { float d = v[i] - mean; sq += d * d; }
#pragma unroll
        for (int off = 32; off; off >>= 1) sq += __shfl_xor(sq, off);
        float r = 1.0f / sqrtf(sq * (1.0f / E) + 1e-5f);
#pragma unroll
        for (int i = 0; i < 8; i++) {
            int e = lane + i * 64;
            float o = (v[i] - mean) * r * g[e] + bb[e];
            xr[e] = o;
            u16 hh, mm, ll; split3(o, hh, mm, ll);
            long idx = (long)row * E + e;
            Xh[idx] = hh; Xm[idx] = mm; Xl[idx] = ll;
        }
    }
}

// ---------- stage: logits ----------
__device__ __noinline__ void stage_logits(const float* __restrict__ X, const float* __restrict__ SW,
                                          const float* __restrict__ sb, float* __restrict__ Lg,
                                          int Seff, int t) {
    __shared__ float red[4][64];
    int nl = threadIdx.x & 63, kq = threadIdx.x >> 6;
    for (int task = blockIdx.x; task < (VOCAB + 63) / 64; task += NWG) {
        int n = task * 64 + nl;
        bool nok = n < VOCAB;
        float acc[BATCH];
#pragma unroll
        for (int b = 0; b < BATCH; b++) acc[b] = 0.f;
        if (nok) {
            int k0 = kq * 128;
            for (int k = k0; k < k0 + 128; k++) {
                float wv = SW[(long)k * VOCAB + n];
#pragma unroll
                for (int b = 0; b < BATCH; b++)
                    acc[b] = fmaf(X[((long)(b * Seff + t)) * E + k], wv, acc[b]);
            }
        }
        for (int b = 0; b < BATCH; b++) {
            red[kq][nl] = acc[b];
            __syncthreads();
            if (kq == 0 && nok)
                Lg[(long)b * VOCAB + n] = red[0][nl] + red[1][nl] + red[2][nl] + red[3][nl] + sb[n];
            __syncthreads();
        }
    }
}

// ---------- stage: softmax -> out, argmax -> Ybuf row t ----------
__device__ __noinline__ void stage_softmax(const float* __restrict__ Lg, float* __restrict__ Out,
                                           const float* __restrict__ w2v, float* __restrict__ Ybuf,
                                           int t) {
    __shared__ float red[256];
    __shared__ float rv[256];
    __shared__ int ri[256];
    int tid = threadIdx.x;
    for (int b = blockIdx.x; b < BATCH; b += NWG) {
        const float* lb = Lg + (long)b * VOCAB;
        float m = -INFINITY;
        for (int n = tid; n < VOCAB; n += 256) m = fmaxf(m, lb[n]);
        red[tid] = m; __syncthreads();
        for (int off = 128; off; off >>= 1) {
            if (tid < off) red[tid] = fmaxf(red[tid], red[tid + off]);
            __syncthreads();
        }
        m = red[0]; __syncthreads();
        float s = 0.f;
        for (int n = tid; n < VOCAB; n += 256) s += expf(lb[n] - m);
        red[tid] = s; __syncthreads();
        for (int off = 128; off; off >>= 1) {
            if (tid < off) red[tid] += red[tid + off];
            __syncthreads();
        }
        s = red[0]; __syncthreads();
        float bestv = -1.0f; int besti = VOCAB;
        float* ob = Out + ((long)b * S_MAX + t) * VOCAB;
        for (int n = tid; n < VOCAB; n += 256) {
            float p = expf(lb[n] - m) / s;
            ob[n] = p;
            if (p > bestv) { bestv = p; besti = n; }
        }
        rv[tid] = bestv; ri[tid] = besti; __syncthreads();
        for (int off = 128; off; off >>= 1) {
            if (tid < off) {
                float v2 = rv[tid + off]; int i2 = ri[tid + off];
                if (v2 > rv[tid] || (v2 == rv[tid] && i2 < ri[tid])) { rv[tid] = v2; ri[tid] = i2; }
            }
            __syncthreads();
        }
        int idx = ri[0];
        float* yb = Ybuf + ((long)b * S_MAX + t) * E;
        for (int e = tid; e < E; e += 256) yb[e] = w2v[(long)idx * E + e];
        __syncthreads();
    }
}

// ---------- megakernel ----------
struct MArgs {
    const float *noise;
    const float *inemb_W, *inemb_b;
    const float *g_attn_W, *g_attn_b, *g_cross_W, *g_cross_b;
    const float *g_ffn_W1, *g_ffn_b1, *g_ffn_W2, *g_ffn_b2, *g_ln_g, *g_ln_b;
    const float *o_attn_W, *o_attn_b, *o_ffn_W1, *o_ffn_b1, *o_ffn_W2, *o_ffn_b2, *o_ln_g, *o_ln_b;
    const float *w2v, *soft_W, *soft_b;
    float *out;
    float *PE, *YBUF, *X, *TMP, *QKV, *KWVW, *LG;
    u16 *XsH, *XsM, *XsL, *AOH, *AOM, *AOL, *HBH, *HBM, *HBL, *WTH, *WTM, *WTL;
    unsigned *bar;
    int full;
};

__global__ __launch_bounds__(NTHR, 1) void mega(MArgs a) {
    const long EE = (long)E * E, EH = (long)E * HID;
    const long BSE = (long)BATCH * S_MAX * E;
    const long OFF_INEMB = 0, OFF_GATTN = 2 * EE, OFF_GCROSS = 10 * EE, OFF_OATTN = 18 * EE,
               OFF_GF1 = 22 * EE, OFF_GF2 = 30 * EE, OFF_OF1 = 38 * EE, OFF_OF2 = 42 * EE;

    auto BAR = [&]() { gridbar(a.bar, a.bar + 1); };
    auto PREP = [&](const float* Ws, long offFull, int K, int N, int Z) -> long {
        if (a.full) return offFull;
        BAR();
        wsplit_one(Ws, a.WTH, a.WTM, a.WTL, K, N, Z);
        BAR();
        return 0;
    };

    // stage 0: PE + (full-mode) all weight splits + noise split — independent outputs
    stage_pe(a.PE);
    if (a.full) {
        wsplit_one(a.inemb_W,  a.WTH + OFF_INEMB,  a.WTM + OFF_INEMB,  a.WTL + OFF_INEMB,  512, 512, 2);
        wsplit_one(a.g_attn_W, a.WTH + OFF_GATTN,  a.WTM + OFF_GATTN,  a.WTL + OFF_GATTN,  512, 512, 8);
        wsplit_one(a.g_cross_W,a.WTH + OFF_GCROSS, a.WTM + OFF_GCROSS, a.WTL + OFF_GCROSS, 512, 512, 8);
        wsplit_one(a.o_attn_W, a.WTH + OFF_OATTN,  a.WTM + OFF_OATTN,  a.WTL + OFF_OATTN,  512, 512, 4);
        wsplit_one(a.g_ffn_W1, a.WTH + OFF_GF1,    a.WTM + OFF_GF1,    a.WTL + OFF_GF1,    512, 2048, 2);
        wsplit_one(a.g_ffn_W2, a.WTH + OFF_GF2,    a.WTM + OFF_GF2,    a.WTL + OFF_GF2,    2048, 512, 2);
        wsplit_one(a.o_ffn_W1, a.WTH + OFF_OF1,    a.WTM + OFF_OF1,    a.WTL + OFF_OF1,    512, 2048, 1);
        wsplit_one(a.o_ffn_W2, a.WTH + OFF_OF2,    a.WTM + OFF_OF2,    a.WTL + OFF_OF2,    2048, 512, 1);
    }
    split_act(a.noise, BSE, a.HBH, a.HBM, a.HBL);
    BAR();

    // inemb chain
    long w = PREP(a.inemb_W, OFF_INEMB, 512, 512, 1);
    stage_gemm<0, 0, 1, 512>(a.HBH, a.HBM, a.HBL, a.WTH + w, a.WTM + w, a.WTL + w, a.inemb_b,
                             nullptr, a.AOH, a.AOM, a.AOL, BATCH * S_MAX, E, 1, 0, 0, 0);
    BAR();
    w = PREP(a.inemb_W + EE, OFF_INEMB + EE, 512, 512, 1);
    stage_gemm<0, 0, 1, 512>(a.AOH, a.AOM, a.AOL, a.WTH + w, a.WTM + w, a.WTL + w, a.inemb_b + E,
                             nullptr, a.XsH, a.XsM, a.XsL, BATCH * S_MAX, E, 1, 0, 0, 0);
    BAR();
    // cross K/V from constant w
    for (int i = 0; i < 2; i++) {
        w = PREP(a.g_cross_W + (i * 4 + 1) * EE, OFF_GCROSS + (i * 4 + 1) * EE, 512, 512, 2);
        stage_gemm<0, 1, 0, 512>(a.XsH, a.XsM, a.XsL, a.WTH + w, a.WTM + w, a.WTL + w,
                                 a.g_cross_b + (i * 4 + 1) * E, a.KWVW + i * 2 * BSE,
                                 nullptr, nullptr, nullptr, BATCH * S_MAX, E, 2, EE, BSE, E);
        BAR();
    }

    for (int t = 0; t < S_MAX; t++) {
        int Seff = t + 1, Mrows = BATCH * Seff;
        long ME = (long)Mrows * E;
        stage_buildx(a.X, a.YBUF, a.PE, Seff, a.XsH, a.XsM, a.XsL);
        BAR();
        for (int i = 0; i < 2; i++) {
            // self-attn
            w = PREP(a.g_attn_W + (long)i * 4 * EE, OFF_GATTN + i * 4 * EE, 512, 512, 3);
            stage_gemm<0, 1, 0, 512>(a.XsH, a.XsM, a.XsL, a.WTH + w, a.WTM + w, a.WTL + w,
                                     a.g_attn_b + (long)i * 4 * E, a.QKV, nullptr, nullptr, nullptr,
                                     Mrows, E, 3, EE, ME, E);
            BAR();
            stage_attn(a.QKV, a.QKV + ME, a.QKV + 2 * ME, a.AOH, a.AOM, a.AOL, Seff, Seff * E);
            BAR();
            w = PREP(a.g_attn_W + (i * 4 + 3) * EE, OFF_GATTN + (i * 4 + 3) * EE, 512, 512, 1);
            stage_gemm<0, 1, 0, 512>(a.AOH, a.AOM, a.AOL, a.WTH + w, a.WTM + w, a.WTL + w,
                                     a.g_attn_b + (i * 4 + 3) * E, a.TMP, nullptr, nullptr, nullptr,
                                     Mrows, E, 1, 0, 0, 0);
            BAR();
            stage_ln(a.X, a.TMP, a.g_ln_g + (i * 3 + 0) * E, a.g_ln_b + (i * 3 + 0) * E,
                     a.XsH, a.XsM, a.XsL, Mrows);
            BAR();
            // cross-attn
            w = PREP(a.g_cross_W + (long)i * 4 * EE, OFF_GCROSS + i * 4 * EE, 512, 512, 1);
            stage_gemm<0, 1, 0, 512>(a.XsH, a.XsM, a.XsL, a.WTH + w, a.WTM + w, a.WTL + w,
                                     a.g_cross_b + (long)i * 4 * E, a.QKV, nullptr, nullptr, nullptr,
                                     Mrows, E, 1, 0, 0, 0);
            BAR();
            stage_attn(a.QKV, a.KWVW + i * 2 * BSE, a.KWVW + i * 2 * BSE + BSE,
                       a.AOH, a.AOM, a.AOL, Seff, S_MAX * E);
            BAR();
            w = PREP(a.g_cross_W + (i * 4 + 3) * EE, OFF_GCROSS + (i * 4 + 3) * EE, 512, 512, 1);
            stage_gemm<0, 1, 0, 512>(a.AOH, a.AOM, a.AOL, a.WTH + w, a.WTM + w, a.WTL + w,
                                     a.g_cross_b + (i * 4 + 3) * E, a.TMP, nullptr, nullptr, nullptr,
                                     Mrows, E, 1, 0, 0, 0);
            BAR();
            stage_ln(a.X, a.TMP, a.g_ln_g + (i * 3 + 1) * E, a.g_ln_b + (i * 3 + 1) * E,
                     a.XsH, a.XsM, a.XsL, Mrows);
            BAR();
            // FFN
            w = PREP(a.g_ffn_W1 + (long)i * EH, OFF_GF1 + i * EH, 512, 2048, 1);
            stage_gemm<1, 0, 1, 512>(a.XsH, a.XsM, a.XsL, a.WTH + w, a.WTM + w, a.WTL + w,
                                     a.g_ffn_b1 + (long)i * HID, nullptr, a.HBH, a.HBM, a.HBL,
                                     Mrows, HID, 1, 0, 0, 0);
            BAR();
            w = PREP(a.g_ffn_W2 + (long)i * EH, OFF_GF2 + i * EH, 2048, 512, 1);
            stage_gemm<0, 1, 0, 2048>(a.HBH, a.HBM, a.HBL, a.WTH + w, a.WTM + w, a.WTL + w,
                                      a.g_ffn_b2 + (long)i * E, a.TMP, nullptr, nullptr, nullptr,
                                      Mrows, E, 1, 0, 0, 0);
            BAR();
            stage_ln(a.X, a.TMP, a.g_ln_g + (i * 3 + 2) * E, a.g_ln_b + (i * 3 + 2) * E,
                     a.XsH, a.XsM, a.XsL, Mrows);
            BAR();
        }
        // o block
        w = PREP(a.o_attn_W, OFF_OATTN, 512, 512, 3);
        stage_gemm<0, 1, 0, 512>(a.XsH, a.XsM, a.XsL, a.WTH + w, a.WTM + w, a.WTL + w,
                                 a.o_attn_b, a.QKV, nullptr, nullptr, nullptr, Mrows, E, 3, EE, ME, E);
        BAR();
        stage_attn(a.QKV, a.QKV + ME, a.QKV + 2 * ME, a.AOH, a.AOM, a.AOL, Seff, Seff * E);
        BAR();
        w = PREP(a.o_attn_W + 3 * EE, OFF_OATTN + 3 * EE, 512, 512, 1);
        stage_gemm<0, 1, 0, 512>(a.AOH, a.AOM, a.AOL, a.WTH + w, a.WTM + w, a.WTL + w,
                                 a.o_attn_b + 3 * E, a.TMP, nullptr, nullptr, nullptr, Mrows, E, 1, 0, 0, 0);
        BAR();
        stage_ln(a.X, a.TMP, a.o_ln_g, a.o_ln_b, a.XsH, a.XsM, a.XsL, Mrows);
        BAR();
        w = PREP(a.o_ffn_W1, OFF_OF1, 512, 2048, 1);
        stage_gemm<1, 0, 1, 512>(a.XsH, a.XsM, a.XsL, a.WTH + w, a.WTM + w, a.WTL + w,
                                 a.o_ffn_b1, nullptr, a.HBH, a.HBM, a.HBL, Mrows, HID, 1, 0, 0, 0);
        BAR();
        w = PREP(a.o_ffn_W2, OFF_OF2, 2048, 512, 1);
        stage_gemm<0, 1, 0, 2048>(a.HBH, a.HBM, a.HBL, a.WTH + w, a.WTM + w, a.WTL + w,
                                  a.o_ffn_b2, a.TMP, nullptr, nullptr, nullptr, Mrows, E, 1, 0, 0, 0);
        BAR();
        stage_ln(a.X, a.TMP, a.o_ln_g + E, a.o_ln_b + E, a.XsH, a.XsM, a.XsL, Mrows);
        BAR();
        stage_logits(a.X, a.soft_W, a.soft_b, a.LG, Seff, t);
        BAR();
        stage_softmax(a.LG, a.out, a.w2v, a.YBUF, t);
        BAR();
    }
}

// =====================================================================
extern "C" void kernel_launch(void* const* d_in, const int* in_sizes, int n_in,
                              void* d_out, int out_size, void* d_ws, size_t ws_size,
                              hipStream_t stream) {
    const float* noise    = (const float*)d_in[0];
    const float* seeds    = (const float*)d_in[1];
    MArgs a;
    a.noise    = noise;
    a.inemb_W  = (const float*)d_in[2];  a.inemb_b  = (const float*)d_in[3];
    a.g_attn_W = (const float*)d_in[4];  a.g_attn_b = (const float*)d_in[5];
    a.g_cross_W= (const float*)d_in[6];  a.g_cross_b= (const float*)d_in[7];
    a.g_ffn_W1 = (const float*)d_in[8];  a.g_ffn_b1 = (const float*)d_in[9];
    a.g_ffn_W2 = (const float*)d_in[10]; a.g_ffn_b2 = (const float*)d_in[11];
    a.g_ln_g   = (const float*)d_in[12]; a.g_ln_b   = (const float*)d_in[13];
    a.o_attn_W = (const float*)d_in[14]; a.o_attn_b = (const float*)d_in[15];
    a.o_ffn_W1 = (const float*)d_in[16]; a.o_ffn_b1 = (const float*)d_in[17];
    a.o_ffn_W2 = (const float*)d_in[18]; a.o_ffn_b2 = (const float*)d_in[19];
    a.o_ln_g   = (const float*)d_in[20]; a.o_ln_b   = (const float*)d_in[21];
    a.w2v      = (const float*)d_in[22];
    a.soft_W   = (const float*)d_in[23]; a.soft_b   = (const float*)d_in[24];
    a.out = (float*)d_out;

    const long EE  = (long)E * E;
    const long BSE = (long)BATCH * S_MAX * E;
    const long BSH = (long)BATCH * S_MAX * HID;
    const long WTOT = 46 * EE;

    float* ws = (float*)d_ws;
    a.bar = (unsigned*)ws;
    float* base = ws + 64;
    long off = 0;
    a.PE   = base + off; off += 16384;
    a.YBUF = base + off; off += BSE;
    a.X    = base + off; off += BSE;
    a.TMP  = base + off; off += BSE;
    a.QKV  = base + off; off += 3 * BSE;
    a.KWVW = base + off; off += 4 * BSE;
    a.LG   = base + off; off += 960000;
    a.XsH = (u16*)(base + off); off += 3 * BSE / 2;
    a.XsM = a.XsH + BSE; a.XsL = a.XsM + BSE;
    a.AOH = (u16*)(base + off); off += 3 * BSE / 2;
    a.AOM = a.AOH + BSE; a.AOL = a.AOM + BSE;
    a.HBH = (u16*)(base + off); off += 3 * BSH / 2;
    a.HBM = a.HBH + BSH; a.HBL = a.HBM + BSH;
    long baseWords = off;

    bool full = ws_size >= (size_t)(64 + baseWords + 3 * WTOT / 2) * 4;
    long WT_ELEMS = full ? WTOT : 4 * EE;
    a.WTH = (u16*)(base + baseWords);
    a.WTM = a.WTH + WT_ELEMS;
    a.WTL = a.WTM + WT_ELEMS;
    a.full = full ? 1 : 0;

    hipMemsetAsync(a.bar, 0, 256, stream);
    hipMemcpyAsync(a.YBUF, seeds, BSE * sizeof(float), hipMemcpyDeviceToDevice, stream);
    mega<<<dim3(NWG), dim3(NTHR), 0, stream>>>(a);
}

// Round 6
// 139422.449 us; speedup vs baseline: 1.0412x; 1.0412x over previous
//
#include <hip/hip_runtime.h>
#include <math.h>

#define E 512
#define S_MAX 32
#define BATCH 32
#define HEADS 8
#define DH 64
#define HID 2048
#define VOCAB 30000
#define NWG 256
#define NTHR 256
#define FSTRIDE 32   // 128B flag spacing

typedef unsigned short u16;
typedef __attribute__((ext_vector_type(8))) short short8;
typedef __attribute__((ext_vector_type(4))) float f32x4;

// ---------- bf16 split helpers (RNE) ----------
__device__ __forceinline__ u16 f2bf(float x) {
    union { float f; unsigned u; } v; v.f = x;
    unsigned r = v.u + 0x7fffu + ((v.u >> 16) & 1u);
    return (u16)(r >> 16);
}
__device__ __forceinline__ float bf2f(u16 h) {
    union { unsigned u; float f; } v; v.u = ((unsigned)h) << 16;
    return v.f;
}
__device__ __forceinline__ void split3(float x, u16& h, u16& m, u16& l) {
    h = f2bf(x); float hf = bf2f(h);
    float r1 = x - hf;
    m = f2bf(r1); float mf = bf2f(m);
    l = f2bf(r1 - mf);
}

// ---------- grid barrier: flag-array, sense via monotonic generation ----------
// flags[i*FSTRIDE] = generation block i arrived at; gen = published generation.
// No contended RMW: arrivals are parallel stores; block0 polls flags in parallel.
__device__ __forceinline__ void gridbar(unsigned* flags, unsigned* gen, unsigned g) {
    __syncthreads();
    if (blockIdx.x == 0) {
        int i = threadIdx.x;              // NTHR == NWG: thread i polls block i
        if (i > 0) {
            while (__hip_atomic_load(&flags[i * FSTRIDE], __ATOMIC_ACQUIRE,
                                     __HIP_MEMORY_SCOPE_AGENT) < g)
                __builtin_amdgcn_s_sleep(1);
        }
        __syncthreads();
        if (threadIdx.x == 0)
            __hip_atomic_store(gen, g, __ATOMIC_RELEASE, __HIP_MEMORY_SCOPE_AGENT);
    } else {
        if (threadIdx.x == 0) {
            __hip_atomic_store(&flags[blockIdx.x * FSTRIDE], g, __ATOMIC_RELEASE,
                               __HIP_MEMORY_SCOPE_AGENT);
            while (__hip_atomic_load(gen, __ATOMIC_ACQUIRE, __HIP_MEMORY_SCOPE_AGENT) < g)
                __builtin_amdgcn_s_sleep(1);
        }
        __syncthreads();
    }
}

// ---------- stage: positional encoding ----------
__device__ __noinline__ void stage_pe(float* __restrict__ PE) {
    for (int i = blockIdx.x * NTHR + threadIdx.x; i < S_MAX * E; i += NWG * NTHR) {
        int s = i >> 9, e = i & (E - 1);
        float expo = (float)(e & ~1) / (float)E;
        float den = powf(10000.0f, expo);
        float ang = (float)s / den;
        PE[i] = (e & 1) ? cosf(ang) : sinf(ang);
    }
}

// ---------- stage: weight split+transpose [K][N]f32 -> [N][K] bf16 x3 ----------
__device__ __noinline__ void wsplit_one(const float* __restrict__ W, u16* __restrict__ Ph,
                                        u16* __restrict__ Pm, u16* __restrict__ Pl,
                                        int K, int N, int Z) {
    long KN = (long)K * N, total = KN * Z;
    for (long i = (long)blockIdx.x * NTHR + threadIdx.x; i < total; i += (long)NWG * NTHR) {
        long z = i / KN; long r = i - z * KN;
        int n = (int)(r / K); int k = (int)(r - (long)n * K);
        float v = W[z * KN + (long)k * N + n];
        u16 h, m, l; split3(v, h, m, l);
        Ph[i] = h; Pm[i] = m; Pl[i] = l;      // i == z*KN + n*K + k
    }
}

// ---------- stage: f32 -> bf16x3 planes ----------
__device__ __noinline__ void split_act(const float* __restrict__ in, long n, u16* __restrict__ Ph,
                                       u16* __restrict__ Pm, u16* __restrict__ Pl) {
    for (long i = (long)blockIdx.x * NTHR + threadIdx.x; i < n; i += (long)NWG * NTHR) {
        u16 h, m, l; split3(in[i], h, m, l);
        Ph[i] = h; Pm[i] = m; Pl[i] = l;
    }
}

// ---------- stage: x = Ybuf + pe (compact), emit splits ----------
__device__ __noinline__ void stage_buildx(float* __restrict__ X, const float* __restrict__ Ybuf,
                                          const float* __restrict__ PE, int Seff,
                                          u16* __restrict__ Xh, u16* __restrict__ Xm,
                                          u16* __restrict__ Xl) {
    long total = (long)BATCH * Seff * E;
    for (long idx = (long)blockIdx.x * NTHR + threadIdx.x; idx < total; idx += (long)NWG * NTHR) {
        int e = (int)(idx & (E - 1));
        long m = idx >> 9;
        int b = (int)(m / Seff);
        int s = (int)(m - (long)b * Seff);
        float v = Ybuf[((long)b * S_MAX + s) * E + e] + PE[s * E + e];
        X[idx] = v;
        u16 h, mm, l; split3(v, h, mm, l);
        Xh[idx] = h; Xm[idx] = mm; Xl[idx] = l;
    }
}

// ---------- stage: MFMA bf16x3-split GEMM (direct-fragment, no LDS) ----------
#define MF(A_, B_, mi, ni) \
    acc[mi][ni] = __builtin_amdgcn_mfma_f32_16x16x32_bf16(A_, B_, acc[mi][ni], 0, 0, 0)

template <int RELU, int WF32, int WSPLIT, int KC>
__device__ __noinline__ void stage_gemm(const u16* __restrict__ Ah, const u16* __restrict__ Am,
                                        const u16* __restrict__ Al,
                                        const u16* __restrict__ Wh, const u16* __restrict__ Wm,
                                        const u16* __restrict__ Wl,
                                        const float* __restrict__ bias,
                                        float* __restrict__ C,
                                        u16* __restrict__ Ch, u16* __restrict__ Cm,
                                        u16* __restrict__ Cl,
                                        int M, int N, int Z, long wz, long cz, long bz) {
    int tid = threadIdx.x, lane = tid & 63, wid = tid >> 6;
    int wr = wid >> 1, wc = wid & 1;
    int mt = (M + 63) >> 6, nt = N >> 6;
    int ntasks = mt * nt * Z;
    for (int task = blockIdx.x; task < ntasks; task += NWG) {
        int z = task / (mt * nt);
        int rr = task - z * mt * nt;
        int tm = rr / nt, tn = rr - tm * nt;
        int m0 = tm * 64, n0 = tn * 64;
        long wzo = (long)z * wz;
        int ra0 = m0 + wr * 32 + (lane & 15); if (ra0 >= M) ra0 = M - 1;
        int ra1 = m0 + wr * 32 + 16 + (lane & 15); if (ra1 >= M) ra1 = M - 1;
        int kcol = (lane >> 4) * 8;
        long ao0 = (long)ra0 * KC + kcol;
        long ao1 = (long)ra1 * KC + kcol;
        long bo0 = (long)(n0 + wc * 32 + (lane & 15)) * KC + kcol + wzo;
        long bo1 = bo0 + 16L * KC;
        f32x4 acc[2][2];
        acc[0][0] = acc[0][1] = acc[1][0] = acc[1][1] = (f32x4){0.f, 0.f, 0.f, 0.f};
#pragma unroll 4
        for (int k0 = 0; k0 < KC; k0 += 32) {
            short8 a0h = *(const short8*)(Ah + ao0 + k0);
            short8 a1h = *(const short8*)(Ah + ao1 + k0);
            short8 a0m = *(const short8*)(Am + ao0 + k0);
            short8 a1m = *(const short8*)(Am + ao1 + k0);
            short8 a0l = *(const short8*)(Al + ao0 + k0);
            short8 a1l = *(const short8*)(Al + ao1 + k0);
            short8 b0h = *(const short8*)(Wh + bo0 + k0);
            short8 b1h = *(const short8*)(Wh + bo1 + k0);
            short8 b0m = *(const short8*)(Wm + bo0 + k0);
            short8 b1m = *(const short8*)(Wm + bo1 + k0);
            short8 b0l = *(const short8*)(Wl + bo0 + k0);
            short8 b1l = *(const short8*)(Wl + bo1 + k0);
            // products: (h,h)(h,m)(m,h)(m,m)(h,l)(l,h)
            MF(a0h, b0h, 0, 0); MF(a0h, b1h, 0, 1); MF(a1h, b0h, 1, 0); MF(a1h, b1h, 1, 1);
            MF(a0h, b0m, 0, 0); MF(a0h, b1m, 0, 1); MF(a1h, b0m, 1, 0); MF(a1h, b1m, 1, 1);
            MF(a0m, b0h, 0, 0); MF(a0m, b1h, 0, 1); MF(a1m, b0h, 1, 0); MF(a1m, b1h, 1, 1);
            MF(a0m, b0m, 0, 0); MF(a0m, b1m, 0, 1); MF(a1m, b0m, 1, 0); MF(a1m, b1m, 1, 1);
            MF(a0h, b0l, 0, 0); MF(a0h, b1l, 0, 1); MF(a1h, b0l, 1, 0); MF(a1h, b1l, 1, 1);
            MF(a0l, b0h, 0, 0); MF(a0l, b1h, 0, 1); MF(a1l, b0h, 1, 0); MF(a1l, b1h, 1, 1);
        }
        const float* bb = bias + (long)z * bz;
        float* Cz = C; u16 *Chz = Ch, *Cmz = Cm, *Clz = Cl;
        if (WF32) Cz = C + (long)z * cz;
        if (WSPLIT) { Chz = Ch + (long)z * cz; Cmz = Cm + (long)z * cz; Clz = Cl + (long)z * cz; }
#pragma unroll
        for (int mi = 0; mi < 2; mi++) {
#pragma unroll
            for (int ni = 0; ni < 2; ni++) {
                int col = n0 + wc * 32 + ni * 16 + (lane & 15);
                float bv = bb[col];
#pragma unroll
                for (int j = 0; j < 4; j++) {
                    int row = m0 + wr * 32 + mi * 16 + (lane >> 4) * 4 + j;
                    if (row < M) {
                        float v = acc[mi][ni][j] + bv;
                        if (RELU) v = fmaxf(v, 0.f);
                        long idx = (long)row * N + col;
                        if (WF32) Cz[idx] = v;
                        if (WSPLIT) {
                            u16 hh, mm, ll; split3(v, hh, mm, ll);
                            Chz[idx] = hh; Cmz[idx] = mm; Clz[idx] = ll;
                        }
                    }
                }
            }
        }
    }
}

// ---------- stage: attention (one wave per (b,h,s) task) ----------
__device__ __noinline__ void stage_attn(const float* __restrict__ Q, const float* __restrict__ Kp,
                                        const float* __restrict__ Vp,
                                        u16* __restrict__ Oh, u16* __restrict__ Om,
                                        u16* __restrict__ Ol,
                                        int Seff, int kvStride) {
    int lane = threadIdx.x & 63;
    int gw = blockIdx.x * 4 + (threadIdx.x >> 6);
    int ntask = Seff * HEADS * BATCH;
    for (int task = gw; task < ntask; task += NWG * 4) {
        int b = task / (Seff * HEADS);
        int r = task - b * Seff * HEADS;
        int h = r / Seff;
        int s = r - h * Seff;
        const float4* q4 = (const float4*)(Q + ((long)(b * Seff + s)) * E + h * DH);
        float sc = -INFINITY;
        if (lane < Seff) {
            const float4* k4 = (const float4*)(Kp + (long)b * kvStride + (long)lane * E + h * DH);
            float acc = 0.f;
#pragma unroll
            for (int d = 0; d < DH / 4; d++) {
                float4 qv = q4[d], kv = k4[d];
                acc += qv.x * kv.x; acc += qv.y * kv.y; acc += qv.z * kv.z; acc += qv.w * kv.w;
            }
            sc = acc * 0.125f;
        }
        float m = sc;
#pragma unroll
        for (int off = 32; off; off >>= 1) m = fmaxf(m, __shfl_xor(m, off));
        float p = (lane < Seff) ? expf(sc - m) : 0.f;
        float sum = p;
#pragma unroll
        for (int off = 32; off; off >>= 1) sum += __shfl_xor(sum, off);
        p = p / sum;
        float accv = 0.f;
        const float* vbase = Vp + (long)b * kvStride + h * DH + lane;
        for (int k = 0; k < Seff; k++) accv = fmaf(__shfl(p, k), vbase[(long)k * E], accv);
        long o = ((long)(b * Seff + s)) * E + h * DH + lane;
        u16 hh, mm, ll; split3(accv, hh, mm, ll);
        Oh[o] = hh; Om[o] = mm; Ol[o] = ll;
    }
}

// ---------- stage: x = LN(x + delta), emit splits (one wave per row) ----------
__device__ __noinline__ void stage_ln(float* __restrict__ X, const float* __restrict__ D,
                                      const float* __restrict__ g, const float* __restrict__ bb,
                                      u16* __restrict__ Xh, u16* __restrict__ Xm,
                                      u16* __restrict__ Xl, int rows) {
    int lane = threadIdx.x & 63;
    for (int row = blockIdx.x * 4 + (threadIdx.x >> 6); row < rows; row += NWG * 4) {
        float* xr = X + (long)row * E;
        const float* dr = D + (long)row * E;
        float v[8]; float s = 0.f;
#pragma unroll
        for (int i = 0; i < 8; i++) { int e = lane + i * 64; v[i] = xr[e] + dr[e]; s += v[i]; }
#pragma unroll
        for (int off = 32; off; off >>= 1) s += __shfl_xor(s, off);
        float mean = s * (1.0f / E);
        float sq = 0.f;
#pragma unroll
        for (int i = 0; i < 8; i++) { float d = v[i] - mean; sq += d * d; }
#pragma unroll
        for (int off = 32; off; off >>= 1) sq += __shfl_xor(sq, off);
        float r = 1.0f / sqrtf(sq * (1.0f / E) + 1e-5f);
#pragma unroll
        for (int i = 0; i < 8; i++) {
            int e = lane + i * 64;
            float o = (v[i] - mean) * r * g[e] + bb[e];
            xr[e] = o;
            u16 hh, mm, ll; split3(o, hh, mm, ll);
            long idx = (long)row * E + e;
            Xh[idx] = hh; Xm[idx] = mm; Xl[idx] = ll;
        }
    }
}

// ---------- stage: logits ----------
__device__ __noinline__ void stage_logits(const float* __restrict__ X, const float* __restrict__ SW,
                                          const float* __restrict__ sb, float* __restrict__ Lg,
                                          int Seff, int t) {
    __shared__ float red[4][64];
    int nl = threadIdx.x & 63, kq = threadIdx.x >> 6;
    for (int task = blockIdx.x; task < (VOCAB + 63) / 64; task += NWG) {
        int n = task * 64 + nl;
        bool nok = n < VOCAB;
        float acc[BATCH];
#pragma unroll
        for (int b = 0; b < BATCH; b++) acc[b] = 0.f;
        if (nok) {
            int k0 = kq * 128;
            for (int k = k0; k < k0 + 128; k++) {
                float wv = SW[(long)k * VOCAB + n];
#pragma unroll
                for (int b = 0; b < BATCH; b++)
                    acc[b] = fmaf(X[((long)(b * Seff + t)) * E + k], wv, acc[b]);
            }
        }
        for (int b = 0; b < BATCH; b++) {
            red[kq][nl] = acc[b];
            __syncthreads();
            if (kq == 0 && nok)
                Lg[(long)b * VOCAB + n] = red[0][nl] + red[1][nl] + red[2][nl] + red[3][nl] + sb[n];
            __syncthreads();
        }
    }
}

// ---------- stage: softmax -> out, argmax -> Ybuf row t ----------
__device__ __noinline__ void stage_softmax(const float* __restrict__ Lg, float* __restrict__ Out,
                                           const float* __restrict__ w2v, float* __restrict__ Ybuf,
                                           int t) {
    __shared__ float red[256];
    __shared__ float rv[256];
    __shared__ int ri[256];
    int tid = threadIdx.x;
    for (int b = blockIdx.x; b < BATCH; b += NWG) {
        const float* lb = Lg + (long)b * VOCAB;
        float m = -INFINITY;
        for (int n = tid; n < VOCAB; n += 256) m = fmaxf(m, lb[n]);
        red[tid] = m; __syncthreads();
        for (int off = 128; off; off >>= 1) {
            if (tid < off) red[tid] = fmaxf(red[tid], red[tid + off]);
            __syncthreads();
        }
        m = red[0]; __syncthreads();
        float s = 0.f;
        for (int n = tid; n < VOCAB; n += 256) s += expf(lb[n] - m);
        red[tid] = s; __syncthreads();
        for (int off = 128; off; off >>= 1) {
            if (tid < off) red[tid] += red[tid + off];
            __syncthreads();
        }
        s = red[0]; __syncthreads();
        float bestv = -1.0f; int besti = VOCAB;
        float* ob = Out + ((long)b * S_MAX + t) * VOCAB;
        for (int n = tid; n < VOCAB; n += 256) {
            float p = expf(lb[n] - m) / s;
            ob[n] = p;
            if (p > bestv) { bestv = p; besti = n; }
        }
        rv[tid] = bestv; ri[tid] = besti; __syncthreads();
        for (int off = 128; off; off >>= 1) {
            if (tid < off) {
                float v2 = rv[tid + off]; int i2 = ri[tid + off];
                if (v2 > rv[tid] || (v2 == rv[tid] && i2 < ri[tid])) { rv[tid] = v2; ri[tid] = i2; }
            }
            __syncthreads();
        }
        int idx = ri[0];
        float* yb = Ybuf + ((long)b * S_MAX + t) * E;
        for (int e = tid; e < E; e += 256) yb[e] = w2v[(long)idx * E + e];
        __syncthreads();
    }
}

// ---------- megakernel ----------
struct MArgs {
    const float *noise;
    const float *inemb_W, *inemb_b;
    const float *g_attn_W, *g_attn_b, *g_cross_W, *g_cross_b;
    const float *g_ffn_W1, *g_ffn_b1, *g_ffn_W2, *g_ffn_b2, *g_ln_g, *g_ln_b;
    const float *o_attn_W, *o_attn_b, *o_ffn_W1, *o_ffn_b1, *o_ffn_W2, *o_ffn_b2, *o_ln_g, *o_ln_b;
    const float *w2v, *soft_W, *soft_b;
    float *out;
    float *PE, *YBUF, *X, *TMP, *QKV, *KWVW, *LG;
    u16 *XsH, *XsM, *XsL, *AOH, *AOM, *AOL, *HBH, *HBM, *HBL, *WTH, *WTM, *WTL;
    unsigned *bar;     // [NWG*FSTRIDE] flags + gen at [NWG*FSTRIDE]
    int full;
};

__global__ __launch_bounds__(NTHR, 1) void mega(MArgs a) {
    const long EE = (long)E * E, EH = (long)E * HID;
    const long BSE = (long)BATCH * S_MAX * E;
    const long OFF_INEMB = 0, OFF_GATTN = 2 * EE, OFF_GCROSS = 10 * EE, OFF_OATTN = 18 * EE,
               OFF_GF1 = 22 * EE, OFF_GF2 = 30 * EE, OFF_OF1 = 38 * EE, OFF_OF2 = 42 * EE;

    unsigned bgen = 0;
    unsigned* flags = a.bar;
    unsigned* gen = a.bar + NWG * FSTRIDE;
    auto BAR = [&]() { gridbar(flags, gen, ++bgen); };
    auto PREP = [&](const float* Ws, long offFull, int K, int N, int Z) -> long {
        if (a.full) return offFull;
        BAR();
        wsplit_one(Ws, a.WTH, a.WTM, a.WTL, K, N, Z);
        BAR();
        return 0;
    };

    // stage 0: PE + (full-mode) all weight splits + noise split — independent outputs
    stage_pe(a.PE);
    if (a.full) {
        wsplit_one(a.inemb_W,  a.WTH + OFF_INEMB,  a.WTM + OFF_INEMB,  a.WTL + OFF_INEMB,  512, 512, 2);
        wsplit_one(a.g_attn_W, a.WTH + OFF_GATTN,  a.WTM + OFF_GATTN,  a.WTL + OFF_GATTN,  512, 512, 8);
        wsplit_one(a.g_cross_W,a.WTH + OFF_GCROSS, a.WTM + OFF_GCROSS, a.WTL + OFF_GCROSS, 512, 512, 8);
        wsplit_one(a.o_attn_W, a.WTH + OFF_OATTN,  a.WTM + OFF_OATTN,  a.WTL + OFF_OATTN,  512, 512, 4);
        wsplit_one(a.g_ffn_W1, a.WTH + OFF_GF1,    a.WTM + OFF_GF1,    a.WTL + OFF_GF1,    512, 2048, 2);
        wsplit_one(a.g_ffn_W2, a.WTH + OFF_GF2,    a.WTM + OFF_GF2,    a.WTL + OFF_GF2,    2048, 512, 2);
        wsplit_one(a.o_ffn_W1, a.WTH + OFF_OF1,    a.WTM + OFF_OF1,    a.WTL + OFF_OF1,    512, 2048, 1);
        wsplit_one(a.o_ffn_W2, a.WTH + OFF_OF2,    a.WTM + OFF_OF2,    a.WTL + OFF_OF2,    2048, 512, 1);
    }
    split_act(a.noise, BSE, a.HBH, a.HBM, a.HBL);
    BAR();

    // inemb chain
    long w = PREP(a.inemb_W, OFF_INEMB, 512, 512, 1);
    stage_gemm<0, 0, 1, 512>(a.HBH, a.HBM, a.HBL, a.WTH + w, a.WTM + w, a.WTL + w, a.inemb_b,
                             nullptr, a.AOH, a.AOM, a.AOL, BATCH * S_MAX, E, 1, 0, 0, 0);
    BAR();
    w = PREP(a.inemb_W + EE, OFF_INEMB + EE, 512, 512, 1);
    stage_gemm<0, 0, 1, 512>(a.AOH, a.AOM, a.AOL, a.WTH + w, a.WTM + w, a.WTL + w, a.inemb_b + E,
                             nullptr, a.XsH, a.XsM, a.XsL, BATCH * S_MAX, E, 1, 0, 0, 0);
    BAR();
    // cross K/V from constant w
    for (int i = 0; i < 2; i++) {
        w = PREP(a.g_cross_W + (i * 4 + 1) * EE, OFF_GCROSS + (i * 4 + 1) * EE, 512, 512, 2);
        stage_gemm<0, 1, 0, 512>(a.XsH, a.XsM, a.XsL, a.WTH + w, a.WTM + w, a.WTL + w,
                                 a.g_cross_b + (i * 4 + 1) * E, a.KWVW + i * 2 * BSE,
                                 nullptr, nullptr, nullptr, BATCH * S_MAX, E, 2, EE, BSE, E);
        BAR();
    }

    for (int t = 0; t < S_MAX; t++) {
        int Seff = t + 1, Mrows = BATCH * Seff;
        long ME = (long)Mrows * E;
        stage_buildx(a.X, a.YBUF, a.PE, Seff, a.XsH, a.XsM, a.XsL);
        BAR();
        for (int i = 0; i < 2; i++) {
            // self-attn
            w = PREP(a.g_attn_W + (long)i * 4 * EE, OFF_GATTN + i * 4 * EE, 512, 512, 3);
            stage_gemm<0, 1, 0, 512>(a.XsH, a.XsM, a.XsL, a.WTH + w, a.WTM + w, a.WTL + w,
                                     a.g_attn_b + (long)i * 4 * E, a.QKV, nullptr, nullptr, nullptr,
                                     Mrows, E, 3, EE, ME, E);
            BAR();
            stage_attn(a.QKV, a.QKV + ME, a.QKV + 2 * ME, a.AOH, a.AOM, a.AOL, Seff, Seff * E);
            BAR();
            w = PREP(a.g_attn_W + (i * 4 + 3) * EE, OFF_GATTN + (i * 4 + 3) * EE, 512, 512, 1);
            stage_gemm<0, 1, 0, 512>(a.AOH, a.AOM, a.AOL, a.WTH + w, a.WTM + w, a.WTL + w,
                                     a.g_attn_b + (i * 4 + 3) * E, a.TMP, nullptr, nullptr, nullptr,
                                     Mrows, E, 1, 0, 0, 0);
            BAR();
            stage_ln(a.X, a.TMP, a.g_ln_g + (i * 3 + 0) * E, a.g_ln_b + (i * 3 + 0) * E,
                     a.XsH, a.XsM, a.XsL, Mrows);
            BAR();
            // cross-attn
            w = PREP(a.g_cross_W + (long)i * 4 * EE, OFF_GCROSS + i * 4 * EE, 512, 512, 1);
            stage_gemm<0, 1, 0, 512>(a.XsH, a.XsM, a.XsL, a.WTH + w, a.WTM + w, a.WTL + w,
                                     a.g_cross_b + (long)i * 4 * E, a.QKV, nullptr, nullptr, nullptr,
                                     Mrows, E, 1, 0, 0, 0);
            BAR();
            stage_attn(a.QKV, a.KWVW + i * 2 * BSE, a.KWVW + i * 2 * BSE + BSE,
                       a.AOH, a.AOM, a.AOL, Seff, S_MAX * E);
            BAR();
            w = PREP(a.g_cross_W + (i * 4 + 3) * EE, OFF_GCROSS + (i * 4 + 3) * EE, 512, 512, 1);
            stage_gemm<0, 1, 0, 512>(a.AOH, a.AOM, a.AOL, a.WTH + w, a.WTM + w, a.WTL + w,
                                     a.g_cross_b + (i * 4 + 3) * E, a.TMP, nullptr, nullptr, nullptr,
                                     Mrows, E, 1, 0, 0, 0);
            BAR();
            stage_ln(a.X, a.TMP, a.g_ln_g + (i * 3 + 1) * E, a.g_ln_b + (i * 3 + 1) * E,
                     a.XsH, a.XsM, a.XsL, Mrows);
            BAR();
            // FFN
            w = PREP(a.g_ffn_W1 + (long)i * EH, OFF_GF1 + i * EH, 512, 2048, 1);
            stage_gemm<1, 0, 1, 512>(a.XsH, a.XsM, a.XsL, a.WTH + w, a.WTM + w, a.WTL + w,
                                     a.g_ffn_b1 + (long)i * HID, nullptr, a.HBH, a.HBM, a.HBL,
                                     Mrows, HID, 1, 0, 0, 0);
            BAR();
            w = PREP(a.g_ffn_W2 + (long)i * EH, OFF_GF2 + i * EH, 2048, 512, 1);
            stage_gemm<0, 1, 0, 2048>(a.HBH, a.HBM, a.HBL, a.WTH + w, a.WTM + w, a.WTL + w,
                                      a.g_ffn_b2 + (long)i * E, a.TMP, nullptr, nullptr, nullptr,
                                      Mrows, E, 1, 0, 0, 0);
            BAR();
            stage_ln(a.X, a.TMP, a.g_ln_g + (i * 3 + 2) * E, a.g_ln_b + (i * 3 + 2) * E,
                     a.XsH, a.XsM, a.XsL, Mrows);
            BAR();
        }
        // o block
        w = PREP(a.o_attn_W, OFF_OATTN, 512, 512, 3);
        stage_gemm<0, 1, 0, 512>(a.XsH, a.XsM, a.XsL, a.WTH + w, a.WTM + w, a.WTL + w,
                                 a.o_attn_b, a.QKV, nullptr, nullptr, nullptr, Mrows, E, 3, EE, ME, E);
        BAR();
        stage_attn(a.QKV, a.QKV + ME, a.QKV + 2 * ME, a.AOH, a.AOM, a.AOL, Seff, Seff * E);
        BAR();
        w = PREP(a.o_attn_W + 3 * EE, OFF_OATTN + 3 * EE, 512, 512, 1);
        stage_gemm<0, 1, 0, 512>(a.AOH, a.AOM, a.AOL, a.WTH + w, a.WTM + w, a.WTL + w,
                                 a.o_attn_b + 3 * E, a.TMP, nullptr, nullptr, nullptr, Mrows, E, 1, 0, 0, 0);
        BAR();
        stage_ln(a.X, a.TMP, a.o_ln_g, a.o_ln_b, a.XsH, a.XsM, a.XsL, Mrows);
        BAR();
        w = PREP(a.o_ffn_W1, OFF_OF1, 512, 2048, 1);
        stage_gemm<1, 0, 1, 512>(a.XsH, a.XsM, a.XsL, a.WTH + w, a.WTM + w, a.WTL + w,
                                 a.o_ffn_b1, nullptr, a.HBH, a.HBM, a.HBL, Mrows, HID, 1, 0, 0, 0);
        BAR();
        w = PREP(a.o_ffn_W2, OFF_OF2, 2048, 512, 1);
        stage_gemm<0, 1, 0, 2048>(a.HBH, a.HBM, a.HBL, a.WTH + w, a.WTM + w, a.WTL + w,
                                  a.o_ffn_b2, a.TMP, nullptr, nullptr, nullptr, Mrows, E, 1, 0, 0, 0);
        BAR();
        stage_ln(a.X, a.TMP, a.o_ln_g + E, a.o_ln_b + E, a.XsH, a.XsM, a.XsL, Mrows);
        BAR();
        stage_logits(a.X, a.soft_W, a.soft_b, a.LG, Seff, t);
        BAR();
        stage_softmax(a.LG, a.out, a.w2v, a.YBUF, t);
        BAR();
    }
}

// =====================================================================
extern "C" void kernel_launch(void* const* d_in, const int* in_sizes, int n_in,
                              void* d_out, int out_size, void* d_ws, size_t ws_size,
                              hipStream_t stream) {
    const float* noise    = (const float*)d_in[0];
    const float* seeds    = (const float*)d_in[1];
    MArgs a;
    a.noise    = noise;
    a.inemb_W  = (const float*)d_in[2];  a.inemb_b  = (const float*)d_in[3];
    a.g_attn_W = (const float*)d_in[4];  a.g_attn_b = (const float*)d_in[5];
    a.g_cross_W= (const float*)d_in[6];  a.g_cross_b= (const float*)d_in[7];
    a.g_ffn_W1 = (const float*)d_in[8];  a.g_ffn_b1 = (const float*)d_in[9];
    a.g_ffn_W2 = (const float*)d_in[10]; a.g_ffn_b2 = (const float*)d_in[11];
    a.g_ln_g   = (const float*)d_in[12]; a.g_ln_b   = (const float*)d_in[13];
    a.o_attn_W = (const float*)d_in[14]; a.o_attn_b = (const float*)d_in[15];
    a.o_ffn_W1 = (const float*)d_in[16]; a.o_ffn_b1 = (const float*)d_in[17];
    a.o_ffn_W2 = (const float*)d_in[18]; a.o_ffn_b2 = (const float*)d_in[19];
    a.o_ln_g   = (const float*)d_in[20]; a.o_ln_b   = (const float*)d_in[21];
    a.w2v      = (const float*)d_in[22];
    a.soft_W   = (const float*)d_in[23]; a.soft_b   = (const float*)d_in[24];
    a.out = (float*)d_out;

    const long EE  = (long)E * E;
    const long BSE = (long)BATCH * S_MAX * E;
    const long BSH = (long)BATCH * S_MAX * HID;
    const long WTOT = 46 * EE;

    float* ws = (float*)d_ws;
    a.bar = (unsigned*)ws;                  // NWG*FSTRIDE flags + gen  (16K u32 = 64KB)
    float* base = ws + 16384;
    long off = 0;
    a.PE   = base + off; off += 16384;
    a.YBUF = base + off; off += BSE;
    a.X    = base + off; off += BSE;
    a.TMP  = base + off; off += BSE;
    a.QKV  = base + off; off += 3 * BSE;
    a.KWVW = base + off; off += 4 * BSE;
    a.LG   = base + off; off += 960000;
    a.XsH = (u16*)(base + off); off += 3 * BSE / 2;
    a.XsM = a.XsH + BSE; a.XsL = a.XsM + BSE;
    a.AOH = (u16*)(base + off); off += 3 * BSE / 2;
    a.AOM = a.AOH + BSE; a.AOL = a.AOM + BSE;
    a.HBH = (u16*)(base + off); off += 3 * BSH / 2;
    a.HBM = a.HBH + BSH; a.HBL = a.HBM + BSH;
    long baseWords = off;

    bool full = ws_size >= (size_t)(16384 + baseWords + 3 * WTOT / 2) * 4;
    long WT_ELEMS = full ? WTOT : 4 * EE;
    a.WTH = (u16*)(base + baseWords);
    a.WTM = a.WTH + WT_ELEMS;
    a.WTL = a.WTM + WT_ELEMS;
    a.full = full ? 1 : 0;

    hipMemsetAsync(a.bar, 0, 65536, stream);
    hipMemcpyAsync(a.YBUF, seeds, BSE * sizeof(float), hipMemcpyDeviceToDevice, stream);
    mega<<<dim3(NWG), dim3(NTHR), 0, stream>>>(a);
}

// Round 7
// 30961.227 us; speedup vs baseline: 4.6885x; 4.5031x over previous
//
#include <hip/hip_runtime.h>
#include <math.h>

#define E 512
#define S_MAX 32
#define BATCH 32
#define HEADS 8
#define DH 64
#define HID 2048
#define VOCAB 30000

typedef unsigned short u16;
typedef __attribute__((ext_vector_type(8))) short short8;
typedef __attribute__((ext_vector_type(4))) float f32x4;

// ---------- bf16 split helpers (RNE) ----------
__device__ __forceinline__ u16 f2bf(float x) {
    union { float f; unsigned u; } v; v.f = x;
    unsigned r = v.u + 0x7fffu + ((v.u >> 16) & 1u);
    return (u16)(r >> 16);
}
__device__ __forceinline__ float bf2f(u16 h) {
    union { unsigned u; float f; } v; v.u = ((unsigned)h) << 16;
    return v.f;
}
__device__ __forceinline__ void split3(float x, u16& h, u16& m, u16& l) {
    h = f2bf(x); float hf = bf2f(h);
    float r1 = x - hf;
    m = f2bf(r1); float mf = bf2f(m);
    l = f2bf(r1 - mf);
}

// ---------------- positional encoding ----------------
__global__ void pe_kernel(float* __restrict__ PEp) {
    int s = blockIdx.x;
    for (int e = threadIdx.x; e < E; e += 256) {
        float expo = (float)(e & ~1) / (float)E;
        float den = powf(10000.0f, expo);
        float ang = (float)s / den;
        PEp[s * E + e] = (e & 1) ? cosf(ang) : sinf(ang);
    }
}

// ---------------- x = Ybuf + pe, also emit bf16x3 planes ----------------
__global__ void build_x_kernel(float* __restrict__ X, const float* __restrict__ Ybuf,
                               const float* __restrict__ PEp, int Seff,
                               u16* __restrict__ Xh, u16* __restrict__ Xm, u16* __restrict__ Xl) {
    long idx = (long)blockIdx.x * 256 + threadIdx.x;
    long total = (long)BATCH * Seff * E;
    if (idx >= total) return;
    int e = (int)(idx & (E - 1));
    long mm = idx >> 9;
    int b = (int)(mm / Seff);
    int s = (int)(mm - (long)b * Seff);
    float v = Ybuf[((long)b * S_MAX + s) * E + e] + PEp[s * E + e];
    X[idx] = v;
    u16 h, m, l; split3(v, h, m, l);
    Xh[idx] = h; Xm[idx] = m; Xl[idx] = l;
}

// ---------------- elementwise f32 -> bf16x3 planes (noise) ----------------
__global__ void split_act_kernel(const float* __restrict__ in, long n,
                                 u16* __restrict__ Ph, u16* __restrict__ Pm, u16* __restrict__ Pl) {
    long i = ((long)blockIdx.x * 256 + threadIdx.x) * 4;
    if (i >= n) return;
    float4 v = *(const float4*)(in + i);
    u16 h, m, l;
    split3(v.x, h, m, l); Ph[i] = h; Pm[i] = m; Pl[i] = l;
    split3(v.y, h, m, l); Ph[i+1] = h; Pm[i+1] = m; Pl[i+1] = l;
    split3(v.z, h, m, l); Ph[i+2] = h; Pm[i+2] = m; Pl[i+2] = l;
    split3(v.w, h, m, l); Ph[i+3] = h; Pm[i+3] = m; Pl[i+3] = l;
}

// ---------------- weight split + transpose: W f32 [K][N] -> 3 bf16 planes [N][K] ----------------
__global__ __launch_bounds__(256) void wsplit_kernel(const float* __restrict__ W,
                                                     u16* __restrict__ Ph, u16* __restrict__ Pm,
                                                     u16* __restrict__ Pl,
                                                     int K, int N, long wzin, long wzout) {
    int z = blockIdx.z;
    W += (long)z * wzin; Ph += (long)z * wzout; Pm += (long)z * wzout; Pl += (long)z * wzout;
    int n0 = blockIdx.x * 32, k0 = blockIdx.y * 32;
    __shared__ float T[32][33];
    int tid = threadIdx.x;
    int kk = tid >> 3, nn = (tid & 7) * 4;
    float4 v = *(const float4*)&W[(long)(k0 + kk) * N + n0 + nn];
    T[kk][nn + 0] = v.x; T[kk][nn + 1] = v.y; T[kk][nn + 2] = v.z; T[kk][nn + 3] = v.w;
    __syncthreads();
    int n = tid >> 3, k4 = (tid & 7) * 4;
    u16 h[4], m[4], l[4];
#pragma unroll
    for (int j = 0; j < 4; j++) split3(T[k4 + j][n], h[j], m[j], l[j]);
    long o = (long)(n0 + n) * K + k0 + k4;
    *(ushort4*)&Ph[o] = make_ushort4(h[0], h[1], h[2], h[3]);
    *(ushort4*)&Pm[o] = make_ushort4(m[0], m[1], m[2], m[3]);
    *(ushort4*)&Pl[o] = make_ushort4(l[0], l[1], l[2], l[3]);
}

// ---------------- MFMA bf16x3-split GEMM, direct-fragment (no LDS, no K-loop barriers) ----------
// C(MxN) = A(MxK) * W(KxN) + bias ; A planes [M][K], W planes [N][K] (pre-transposed)
// grid (N/64, ceil(M/64), Z); 4 waves (2x2) of 32x32 per block. Validated in rounds 5/6.
#define MF(A_, B_, mi, ni) \
    acc[mi][ni] = __builtin_amdgcn_mfma_f32_16x16x32_bf16(A_, B_, acc[mi][ni], 0, 0, 0)

template <int RELU, int WF32, int WSPLIT, int KC>
__global__ __launch_bounds__(256) void gemm_direct(
    const u16* __restrict__ Ah, const u16* __restrict__ Am, const u16* __restrict__ Al,
    const u16* __restrict__ Wh, const u16* __restrict__ Wm, const u16* __restrict__ Wl,
    const float* __restrict__ bias,
    float* __restrict__ C, u16* __restrict__ Ch, u16* __restrict__ Cm, u16* __restrict__ Cl,
    int M, int N, long wz, long cz, long bz) {
    int z = blockIdx.z;
    const u16* Whz = Wh + (long)z * wz;
    const u16* Wmz = Wm + (long)z * wz;
    const u16* Wlz = Wl + (long)z * wz;
    const float* bb = bias + (long)z * bz;

    int n0 = blockIdx.x * 64, m0 = blockIdx.y * 64;
    int lane = threadIdx.x & 63, wid = threadIdx.x >> 6;
    int wr = wid >> 1, wc = wid & 1;

    int ra0 = m0 + wr * 32 + (lane & 15); if (ra0 >= M) ra0 = M - 1;
    int ra1 = m0 + wr * 32 + 16 + (lane & 15); if (ra1 >= M) ra1 = M - 1;
    int kcol = (lane >> 4) * 8;
    long ao0 = (long)ra0 * KC + kcol;
    long ao1 = (long)ra1 * KC + kcol;
    long bo0 = (long)(n0 + wc * 32 + (lane & 15)) * KC + kcol;
    long bo1 = bo0 + 16L * KC;

    f32x4 acc[2][2];
    acc[0][0] = acc[0][1] = acc[1][0] = acc[1][1] = (f32x4){0.f, 0.f, 0.f, 0.f};

#pragma unroll 4
    for (int k0 = 0; k0 < KC; k0 += 32) {
        short8 a0h = *(const short8*)(Ah + ao0 + k0);
        short8 a1h = *(const short8*)(Ah + ao1 + k0);
        short8 a0m = *(const short8*)(Am + ao0 + k0);
        short8 a1m = *(const short8*)(Am + ao1 + k0);
        short8 a0l = *(const short8*)(Al + ao0 + k0);
        short8 a1l = *(const short8*)(Al + ao1 + k0);
        short8 b0h = *(const short8*)(Whz + bo0 + k0);
        short8 b1h = *(const short8*)(Whz + bo1 + k0);
        short8 b0m = *(const short8*)(Wmz + bo0 + k0);
        short8 b1m = *(const short8*)(Wmz + bo1 + k0);
        short8 b0l = *(const short8*)(Wlz + bo0 + k0);
        short8 b1l = *(const short8*)(Wlz + bo1 + k0);
        // products: (h,h)(h,m)(m,h)(m,m)(h,l)(l,h)
        MF(a0h, b0h, 0, 0); MF(a0h, b1h, 0, 1); MF(a1h, b0h, 1, 0); MF(a1h, b1h, 1, 1);
        MF(a0h, b0m, 0, 0); MF(a0h, b1m, 0, 1); MF(a1h, b0m, 1, 0); MF(a1h, b1m, 1, 1);
        MF(a0m, b0h, 0, 0); MF(a0m, b1h, 0, 1); MF(a1m, b0h, 1, 0); MF(a1m, b1h, 1, 1);
        MF(a0m, b0m, 0, 0); MF(a0m, b1m, 0, 1); MF(a1m, b0m, 1, 0); MF(a1m, b1m, 1, 1);
        MF(a0h, b0l, 0, 0); MF(a0h, b1l, 0, 1); MF(a1h, b0l, 1, 0); MF(a1h, b1l, 1, 1);
        MF(a0l, b0h, 0, 0); MF(a0l, b1h, 0, 1); MF(a1l, b0h, 1, 0); MF(a1l, b1h, 1, 1);
    }

    float* Cz = C; u16 *Chz = Ch, *Cmz = Cm, *Clz = Cl;
    if (WF32) Cz = C + (long)z * cz;
    if (WSPLIT) { Chz = Ch + (long)z * cz; Cmz = Cm + (long)z * cz; Clz = Cl + (long)z * cz; }
    // epilogue: D col = lane&15, row = (lane>>4)*4 + reg  [m89-verified]
#pragma unroll
    for (int mi = 0; mi < 2; mi++) {
#pragma unroll
        for (int ni = 0; ni < 2; ni++) {
            int col = n0 + wc * 32 + ni * 16 + (lane & 15);
            float bv = bb[col];
#pragma unroll
            for (int j = 0; j < 4; j++) {
                int row = m0 + wr * 32 + mi * 16 + (lane >> 4) * 4 + j;
                if (row < M) {
                    float v = acc[mi][ni][j] + bv;
                    if (RELU) v = fmaxf(v, 0.f);
                    long idx = (long)row * N + col;
                    if (WF32) Cz[idx] = v;
                    if (WSPLIT) {
                        u16 hh, mm, ll; split3(v, hh, mm, ll);
                        Chz[idx] = hh; Cmz[idx] = mm; Clz[idx] = ll;
                    }
                }
            }
        }
    }
}

// ---------------- attention: one (q-row, head, batch) per 64-thread block ----------------
__global__ __launch_bounds__(64) void attn_kernel(const float* __restrict__ Q,
                                                  const float* __restrict__ Kp,
                                                  const float* __restrict__ Vp,
                                                  u16* __restrict__ Oh, u16* __restrict__ Om,
                                                  u16* __restrict__ Ol,
                                                  int Seff, int kvBatchStride) {
    int s = blockIdx.x, h = blockIdx.y, b = blockIdx.z;
    int lane = threadIdx.x;
    __shared__ float qs[DH];
    qs[lane] = Q[((long)(b * Seff + s)) * E + h * DH + lane];
    __syncthreads();

    float sc = -INFINITY;
    if (lane < Seff) {
        const float4* k4 = (const float4*)(Kp + (long)b * kvBatchStride + (long)lane * E + h * DH);
        const float4* q4 = (const float4*)qs;
        float acc = 0.f;
#pragma unroll
        for (int d = 0; d < DH / 4; d++) {
            float4 kv = k4[d];
            float4 qv = q4[d];
            acc += qv.x * kv.x; acc += qv.y * kv.y; acc += qv.z * kv.z; acc += qv.w * kv.w;
        }
        sc = acc * 0.125f;
    }
    float m = sc;
#pragma unroll
    for (int off = 32; off; off >>= 1) m = fmaxf(m, __shfl_xor(m, off));
    float p = (lane < Seff) ? expf(sc - m) : 0.f;
    float sum = p;
#pragma unroll
    for (int off = 32; off; off >>= 1) sum += __shfl_xor(sum, off);
    p = p / sum;

    float acc = 0.f;
    const float* vbase = Vp + (long)b * kvBatchStride + h * DH + lane;
    for (int k = 0; k < Seff; k++) {
        float pk = __shfl(p, k);
        acc = fmaf(pk, vbase[(long)k * E], acc);
    }
    long o = ((long)(b * Seff + s)) * E + h * DH + lane;
    u16 hh, mm, ll; split3(acc, hh, mm, ll);
    Oh[o] = hh; Om[o] = mm; Ol[o] = ll;
}

// ---------------- x = LN(x + delta), also emit splits ----------------
__global__ __launch_bounds__(64) void resid_ln_kernel(float* __restrict__ X,
                                                      const float* __restrict__ Dlt,
                                                      const float* __restrict__ g,
                                                      const float* __restrict__ bb,
                                                      u16* __restrict__ Xh, u16* __restrict__ Xm,
                                                      u16* __restrict__ Xl) {
    long row = blockIdx.x;
    int lane = threadIdx.x;
    float* xr = X + row * E;
    const float* dr = Dlt + row * E;
    float v[8];
    float s = 0.f;
#pragma unroll
    for (int i = 0; i < 8; i++) {
        int e = lane + i * 64;
        v[i] = xr[e] + dr[e];
        s += v[i];
    }
#pragma unroll
    for (int off = 32; off; off >>= 1) s += __shfl_xor(s, off);
    float mean = s * (1.0f / E);
    float sq = 0.f;
#pragma unroll
    for (int i = 0; i < 8; i++) {
        float d = v[i] - mean;
        sq += d * d;
    }
#pragma unroll
    for (int off = 32; off; off >>= 1) sq += __shfl_xor(sq, off);
    float var = sq * (1.0f / E);
    float r = 1.0f / sqrtf(var + 1e-5f);
#pragma unroll
    for (int i = 0; i < 8; i++) {
        int e = lane + i * 64;
        float o = (v[i] - mean) * r * g[e] + bb[e];
        xr[e] = o;
        u16 hh, mm, ll; split3(o, hh, mm, ll);
        long idx = row * E + e;
        Xh[idx] = hh; Xm[idx] = mm; Xl[idx] = ll;
    }
}

// ---------------- logits = tok(B x E) @ soft_W(E x V) + soft_b ----------------
__global__ __launch_bounds__(256) void logits_kernel(const float* __restrict__ X,
                                                     const float* __restrict__ SW,
                                                     const float* __restrict__ sb,
                                                     float* __restrict__ Lg,
                                                     int Seff, int t) {
    int nl = threadIdx.x & 63;
    int kq = threadIdx.x >> 6;
    int n = blockIdx.x * 64 + nl;
    bool nok = n < VOCAB;
    float acc[BATCH];
#pragma unroll
    for (int b = 0; b < BATCH; b++) acc[b] = 0.f;
    if (nok) {
        int k0 = kq * 128;
        for (int k = k0; k < k0 + 128; k++) {
            float wv = SW[(long)k * VOCAB + n];
#pragma unroll
            for (int b = 0; b < BATCH; b++) {
                acc[b] = fmaf(X[((long)(b * Seff + t)) * E + k], wv, acc[b]);
            }
        }
    }
    __shared__ float red[4][64];
    for (int b = 0; b < BATCH; b++) {
        red[kq][nl] = acc[b];
        __syncthreads();
        if (kq == 0 && nok) {
            float sum = red[0][nl] + red[1][nl] + red[2][nl] + red[3][nl] + sb[n];
            Lg[(long)b * VOCAB + n] = sum;
        }
        __syncthreads();
    }
}

// ---------------- softmax -> out[:,t,:], argmax -> Ybuf[:,t,:] = w2v[idx] ----------------
__global__ __launch_bounds__(256) void softmax_out_kernel(const float* __restrict__ Lg,
                                                          float* __restrict__ Out,
                                                          const float* __restrict__ w2v,
                                                          float* __restrict__ Ybuf, int t) {
    int b = blockIdx.x;
    int tid = threadIdx.x;
    const float* lb = Lg + (long)b * VOCAB;
    __shared__ float red[256];

    float m = -INFINITY;
    for (int n = tid; n < VOCAB; n += 256) m = fmaxf(m, lb[n]);
    red[tid] = m;
    __syncthreads();
    for (int off = 128; off; off >>= 1) {
        if (tid < off) red[tid] = fmaxf(red[tid], red[tid + off]);
        __syncthreads();
    }
    m = red[0];
    __syncthreads();

    float s = 0.f;
    for (int n = tid; n < VOCAB; n += 256) s += expf(lb[n] - m);
    red[tid] = s;
    __syncthreads();
    for (int off = 128; off; off >>= 1) {
        if (tid < off) red[tid] += red[tid + off];
        __syncthreads();
    }
    s = red[0];
    __syncthreads();

    float bestv = -1.0f;
    int besti = VOCAB;
    float* ob = Out + ((long)b * S_MAX + t) * VOCAB;
    for (int n = tid; n < VOCAB; n += 256) {
        float p = expf(lb[n] - m) / s;
        ob[n] = p;
        if (p > bestv) { bestv = p; besti = n; }
    }
    __shared__ float rv[256];
    __shared__ int ri[256];
    rv[tid] = bestv;
    ri[tid] = besti;
    __syncthreads();
    for (int off = 128; off; off >>= 1) {
        if (tid < off) {
            float v2 = rv[tid + off];
            int i2 = ri[tid + off];
            if (v2 > rv[tid] || (v2 == rv[tid] && i2 < ri[tid])) { rv[tid] = v2; ri[tid] = i2; }
        }
        __syncthreads();
    }
    int idx = ri[0];
    float* yb = Ybuf + ((long)b * S_MAX + t) * E;
    for (int e = tid; e < E; e += 256) yb[e] = w2v[(long)idx * E + e];
}

// =====================================================================
extern "C" void kernel_launch(void* const* d_in, const int* in_sizes, int n_in,
                              void* d_out, int out_size, void* d_ws, size_t ws_size,
                              hipStream_t stream) {
    const float* noise    = (const float*)d_in[0];
    const float* seeds    = (const float*)d_in[1];
    const float* inemb_W  = (const float*)d_in[2];
    const float* inemb_b  = (const float*)d_in[3];
    const float* g_attn_W = (const float*)d_in[4];
    const float* g_attn_b = (const float*)d_in[5];
    const float* g_cross_W= (const float*)d_in[6];
    const float* g_cross_b= (const float*)d_in[7];
    const float* g_ffn_W1 = (const float*)d_in[8];
    const float* g_ffn_b1 = (const float*)d_in[9];
    const float* g_ffn_W2 = (const float*)d_in[10];
    const float* g_ffn_b2 = (const float*)d_in[11];
    const float* g_ln_g   = (const float*)d_in[12];
    const float* g_ln_b   = (const float*)d_in[13];
    const float* o_attn_W = (const float*)d_in[14];
    const float* o_attn_b = (const float*)d_in[15];
    const float* o_ffn_W1 = (const float*)d_in[16];
    const float* o_ffn_b1 = (const float*)d_in[17];
    const float* o_ffn_W2 = (const float*)d_in[18];
    const float* o_ffn_b2 = (const float*)d_in[19];
    const float* o_ln_g   = (const float*)d_in[20];
    const float* o_ln_b   = (const float*)d_in[21];
    const float* w2v      = (const float*)d_in[22];
    const float* soft_W   = (const float*)d_in[23];
    const float* soft_b   = (const float*)d_in[24];
    float* out = (float*)d_out;
    float* ws = (float*)d_ws;

    const long EE  = (long)E * E;                 // 262144
    const long EH  = (long)E * HID;               // 1048576
    const long BSE = (long)BATCH * S_MAX * E;     // 524288
    const long BSH = (long)BATCH * S_MAX * HID;   // 2097152
    const long WTOT = 46 * EE;                    // 12058624 elems per plane (full split)

    // ---- workspace layout (f32 words) ----
    long off = 0;
    float* PE   = ws + off; off += 16384;
    float* YBUF = ws + off; off += BSE;
    float* X    = ws + off; off += BSE;
    float* TMP  = ws + off; off += BSE;
    float* QKV  = ws + off; off += 3 * BSE;
    float* KWVW = ws + off; off += 4 * BSE;
    float* LG   = ws + off; off += 960000;
    u16* XsH = (u16*)(ws + off); off += 3 * BSE / 2;
    u16* XsM = XsH + BSE; u16* XsL = XsM + BSE;
    u16* AOH = (u16*)(ws + off); off += 3 * BSE / 2;
    u16* AOM = AOH + BSE; u16* AOL = AOM + BSE;
    u16* HBH = (u16*)(ws + off); off += 3 * BSH / 2;
    u16* HBM2 = HBH + BSH; u16* HBL = HBM2 + BSH;
    long baseWords = off;

    bool full = ws_size >= (size_t)(baseWords + 3 * WTOT / 2) * 4;
    long WT_ELEMS = full ? WTOT : 4 * EE;
    u16* WT_H = (u16*)(ws + baseWords);
    u16* WT_M = WT_H + WT_ELEMS;
    u16* WT_L = WT_M + WT_ELEMS;

    // weight-plane offsets (full mode)
    const long OFF_INEMB = 0;
    const long OFF_GATTN = 2 * EE;
    const long OFF_GCROSS = 10 * EE;
    const long OFF_OATTN = 18 * EE;
    const long OFF_GF1 = 22 * EE;
    const long OFF_GF2 = 30 * EE;
    const long OFF_OF1 = 38 * EE;
    const long OFF_OF2 = 42 * EE;

    // split (fallback: on demand) ; returns plane offset to use
    auto WSPL = [&](const float* Wsrc, long offFull, int K, int N, int z) -> long {
        if (full) return offFull;
        wsplit_kernel<<<dim3(N / 32, K / 32, z), dim3(256), 0, stream>>>(
            Wsrc, WT_H, WT_M, WT_L, K, N, (long)K * N, (long)K * N);
        return 0;
    };

    // mode: 0 = f32 out, 1 = split out, 2 = relu + split out
    auto GEMM = [&](const u16* Ah, const u16* Am, const u16* Al, long woff,
                    const float* bias, float* C, u16* Ch, u16* Cm, u16* Cl,
                    int M, int N, int K, int Z, long wz, long cz, long bz, int mode) {
        dim3 g(N / 64, (M + 63) / 64, Z);
        const u16* Wh = WT_H + woff; const u16* Wm = WT_M + woff; const u16* Wl = WT_L + woff;
        if (K == 512) {
            if (mode == 0)
                gemm_direct<0, 1, 0, 512><<<g, dim3(256), 0, stream>>>(
                    Ah, Am, Al, Wh, Wm, Wl, bias, C, Ch, Cm, Cl, M, N, wz, cz, bz);
            else if (mode == 1)
                gemm_direct<0, 0, 1, 512><<<g, dim3(256), 0, stream>>>(
                    Ah, Am, Al, Wh, Wm, Wl, bias, C, Ch, Cm, Cl, M, N, wz, cz, bz);
            else
                gemm_direct<1, 0, 1, 512><<<g, dim3(256), 0, stream>>>(
                    Ah, Am, Al, Wh, Wm, Wl, bias, C, Ch, Cm, Cl, M, N, wz, cz, bz);
        } else {  // K == 2048, mode 0 only (FFN2)
            gemm_direct<0, 1, 0, 2048><<<g, dim3(256), 0, stream>>>(
                Ah, Am, Al, Wh, Wm, Wl, bias, C, Ch, Cm, Cl, M, N, wz, cz, bz);
        }
    };

    // ---- preamble ----
    pe_kernel<<<dim3(S_MAX), dim3(256), 0, stream>>>(PE);
    hipMemcpyAsync(YBUF, seeds, BSE * sizeof(float), hipMemcpyDeviceToDevice, stream);

    if (full) {
        wsplit_kernel<<<dim3(16, 16, 2), dim3(256), 0, stream>>>(inemb_W, WT_H + OFF_INEMB, WT_M + OFF_INEMB, WT_L + OFF_INEMB, 512, 512, EE, EE);
        wsplit_kernel<<<dim3(16, 16, 8), dim3(256), 0, stream>>>(g_attn_W, WT_H + OFF_GATTN, WT_M + OFF_GATTN, WT_L + OFF_GATTN, 512, 512, EE, EE);
        wsplit_kernel<<<dim3(16, 16, 8), dim3(256), 0, stream>>>(g_cross_W, WT_H + OFF_GCROSS, WT_M + OFF_GCROSS, WT_L + OFF_GCROSS, 512, 512, EE, EE);
        wsplit_kernel<<<dim3(16, 16, 4), dim3(256), 0, stream>>>(o_attn_W, WT_H + OFF_OATTN, WT_M + OFF_OATTN, WT_L + OFF_OATTN, 512, 512, EE, EE);
        wsplit_kernel<<<dim3(64, 16, 2), dim3(256), 0, stream>>>(g_ffn_W1, WT_H + OFF_GF1, WT_M + OFF_GF1, WT_L + OFF_GF1, 512, 2048, EH, EH);
        wsplit_kernel<<<dim3(16, 64, 2), dim3(256), 0, stream>>>(g_ffn_W2, WT_H + OFF_GF2, WT_M + OFF_GF2, WT_L + OFF_GF2, 2048, 512, EH, EH);
        wsplit_kernel<<<dim3(64, 16, 1), dim3(256), 0, stream>>>(o_ffn_W1, WT_H + OFF_OF1, WT_M + OFF_OF1, WT_L + OFF_OF1, 512, 2048, EH, EH);
        wsplit_kernel<<<dim3(16, 64, 1), dim3(256), 0, stream>>>(o_ffn_W2, WT_H + OFF_OF2, WT_M + OFF_OF2, WT_L + OFF_OF2, 2048, 512, EH, EH);
    }

    // noise splits (into HB planes, free until step 0's FFN1)
    split_act_kernel<<<dim3((int)(BSE / 1024)), dim3(256), 0, stream>>>(noise, BSE, HBH, HBM2, HBL);

    // inemb: two chained E x E GEMMs -> WEMB splits (in Xs planes)
    {
        long w = WSPL(inemb_W, OFF_INEMB, 512, 512, 1);
        GEMM(HBH, HBM2, HBL, w, inemb_b, TMP, AOH, AOM, AOL, BATCH * S_MAX, E, E, 1, 0, 0, 0, 1);
        w = WSPL(inemb_W + EE, OFF_INEMB + EE, 512, 512, 1);
        GEMM(AOH, AOM, AOL, w, inemb_b + E, TMP, XsH, XsM, XsL, BATCH * S_MAX, E, E, 1, 0, 0, 0, 1);
    }
    // cross K/V from constant w (full-S, f32 out)
    for (int i = 0; i < 2; i++) {
        long w = WSPL(g_cross_W + (i * 4 + 1) * EE, OFF_GCROSS + (i * 4 + 1) * EE, 512, 512, 2);
        GEMM(XsH, XsM, XsL, w, g_cross_b + (i * 4 + 1) * E, KWVW + i * 2 * BSE, AOH, AOM, AOL,
             BATCH * S_MAX, E, E, 2, EE, BSE, E, 0);
    }

    // ---- autoregressive scan ----
    for (int t = 0; t < S_MAX; t++) {
        int Seff = t + 1;
        int Mrows = BATCH * Seff;
        long ME = (long)Mrows * E;
        int total = Mrows * E;

        build_x_kernel<<<dim3((total + 255) / 256), dim3(256), 0, stream>>>(X, YBUF, PE, Seff,
                                                                            XsH, XsM, XsL);

        for (int i = 0; i < 2; i++) {
            // self-attn
            long w = WSPL(g_attn_W + (long)i * 4 * EE, OFF_GATTN + i * 4 * EE, 512, 512, 3);
            GEMM(XsH, XsM, XsL, w, g_attn_b + (long)i * 4 * E, QKV, AOH, AOM, AOL,
                 Mrows, E, E, 3, EE, ME, E, 0);
            attn_kernel<<<dim3(Seff, HEADS, BATCH), dim3(64), 0, stream>>>(
                QKV, QKV + ME, QKV + 2 * ME, AOH, AOM, AOL, Seff, Seff * E);
            w = WSPL(g_attn_W + (i * 4 + 3) * EE, OFF_GATTN + (i * 4 + 3) * EE, 512, 512, 1);
            GEMM(AOH, AOM, AOL, w, g_attn_b + (i * 4 + 3) * E, TMP, AOH, AOM, AOL,
                 Mrows, E, E, 1, 0, 0, 0, 0);
            resid_ln_kernel<<<dim3(Mrows), dim3(64), 0, stream>>>(
                X, TMP, g_ln_g + (i * 3 + 0) * E, g_ln_b + (i * 3 + 0) * E, XsH, XsM, XsL);
            // cross-attn
            w = WSPL(g_cross_W + (long)i * 4 * EE, OFF_GCROSS + i * 4 * EE, 512, 512, 1);
            GEMM(XsH, XsM, XsL, w, g_cross_b + (long)i * 4 * E, QKV, AOH, AOM, AOL,
                 Mrows, E, E, 1, 0, 0, 0, 0);
            attn_kernel<<<dim3(Seff, HEADS, BATCH), dim3(64), 0, stream>>>(
                QKV, KWVW + i * 2 * BSE, KWVW + i * 2 * BSE + BSE, AOH, AOM, AOL, Seff, S_MAX * E);
            w = WSPL(g_cross_W + (i * 4 + 3) * EE, OFF_GCROSS + (i * 4 + 3) * EE, 512, 512, 1);
            GEMM(AOH, AOM, AOL, w, g_cross_b + (i * 4 + 3) * E, TMP, AOH, AOM, AOL,
                 Mrows, E, E, 1, 0, 0, 0, 0);
            resid_ln_kernel<<<dim3(Mrows), dim3(64), 0, stream>>>(
                X, TMP, g_ln_g + (i * 3 + 1) * E, g_ln_b + (i * 3 + 1) * E, XsH, XsM, XsL);
            // FFN
            w = WSPL(g_ffn_W1 + (long)i * EH, OFF_GF1 + i * EH, 512, 2048, 1);
            GEMM(XsH, XsM, XsL, w, g_ffn_b1 + (long)i * HID, TMP, HBH, HBM2, HBL,
                 Mrows, HID, E, 1, 0, 0, 0, 2);
            w = WSPL(g_ffn_W2 + (long)i * EH, OFF_GF2 + i * EH, 2048, 512, 1);
            GEMM(HBH, HBM2, HBL, w, g_ffn_b2 + (long)i * E, TMP, AOH, AOM, AOL,
                 Mrows, E, HID, 1, 0, 0, 0, 0);
            resid_ln_kernel<<<dim3(Mrows), dim3(64), 0, stream>>>(
                X, TMP, g_ln_g + (i * 3 + 2) * E, g_ln_b + (i * 3 + 2) * E, XsH, XsM, XsL);
        }
        // o block
        {
            long w = WSPL(o_attn_W, OFF_OATTN, 512, 512, 3);
            GEMM(XsH, XsM, XsL, w, o_attn_b, QKV, AOH, AOM, AOL, Mrows, E, E, 3, EE, ME, E, 0);
            attn_kernel<<<dim3(Seff, HEADS, BATCH), dim3(64), 0, stream>>>(
                QKV, QKV + ME, QKV + 2 * ME, AOH, AOM, AOL, Seff, Seff * E);
            w = WSPL(o_attn_W + 3 * EE, OFF_OATTN + 3 * EE, 512, 512, 1);
            GEMM(AOH, AOM, AOL, w, o_attn_b + 3 * E, TMP, AOH, AOM, AOL, Mrows, E, E, 1, 0, 0, 0, 0);
            resid_ln_kernel<<<dim3(Mrows), dim3(64), 0, stream>>>(X, TMP, o_ln_g, o_ln_b,
                                                                  XsH, XsM, XsL);
            w = WSPL(o_ffn_W1, OFF_OF1, 512, 2048, 1);
            GEMM(XsH, XsM, XsL, w, o_ffn_b1, TMP, HBH, HBM2, HBL, Mrows, HID, E, 1, 0, 0, 0, 2);
            w = WSPL(o_ffn_W2, OFF_OF2, 2048, 512, 1);
            GEMM(HBH, HBM2, HBL, w, o_ffn_b2, TMP, AOH, AOM, AOL, Mrows, E, HID, 1, 0, 0, 0, 0);
            resid_ln_kernel<<<dim3(Mrows), dim3(64), 0, stream>>>(X, TMP, o_ln_g + E, o_ln_b + E,
                                                                  XsH, XsM, XsL);
        }

        logits_kernel<<<dim3((VOCAB + 63) / 64), dim3(256), 0, stream>>>(X, soft_W, soft_b, LG, Seff, t);
        softmax_out_kernel<<<dim3(BATCH), dim3(256), 0, stream>>>(LG, out, w2v, YBUF, t);
    }
}